// Round 4
// baseline (315.316 us; speedup 1.0000x reference)
//
#include <hip/hip_runtime.h>
#include <stdint.h>

typedef unsigned long long u64;
typedef unsigned int u32;

#define FH 37
#define FW 62
#define NA 9
#define NPRED (FH*FW*NA)   // 20646
#define BS 4
#define KEEP_PRE 6000
#define KEEP_POST 300
#define NBINS 65536        // top 16 bits of order-mapped pred
#define SLOTCAP 8192
#define NCHUNK ((NPRED + 1023) / 1024)  // 21
#define NBLK ((KEEP_PRE + 63) / 64)     // 94

// global ws: hist, suffix (pristine), cursor (mutable) — u32[BS][NBINS] each
#define OFF_HIST   0u
#define OFF_SUFFIX (BS*NBINS*4u)
#define OFF_CURSOR (2u*BS*NBINS*4u)
#define WS_NEEDED  (3u*BS*NBINS*4u)     // 3 MB

// ---------------------------------------------------------------------------
// helpers
// ---------------------------------------------------------------------------
__device__ __forceinline__ float bcast(float v, int srcLane) {
  return __int_as_float(__builtin_amdgcn_readlane(__float_as_int(v), srcLane));
}

// suppression test: kept box (k) vs candidate (c). Same op structure as the
// validated rounds 0-3 kernels (absmax=0): un = kept_area + cand_area - inter.
__device__ __forceinline__ bool iou_sup(float kx1, float ky1, float kx2, float ky2,
                                        float ka, float cx1, float cy1,
                                        float cx2, float cy2, float ca) {
  float wx = fmaxf(fminf(kx2, cx2) - fmaxf(kx1, cx1), 0.f);
  float wy = fmaxf(fminf(ky2, cy2) - fmaxf(ky1, cy1), 0.f);
  float inter = wx * wy;
  float un = ka + ca - inter;
  return inter > 0.7f * fmaxf(un, 1e-9f);
}
__device__ __forceinline__ bool iou_sup_box(float4 kb, float4 c, float ca) {
  float ka = fmaxf(kb.z - kb.x, 0.f) * fmaxf(kb.w - kb.y, 0.f);
  return iou_sup(kb.x, kb.y, kb.z, kb.w, ka, c.x, c.y, c.z, c.w, ca);
}

// box decode — textually identical formula to rounds 0-3 prep (absmax=0);
// now the single decode site in the program.
__device__ __forceinline__ float4 decode_box(u32 n, float4 d, float W, float H) {
  int a = (int)(n % NA);
  int cell = (int)(n / NA);
  int x = cell % FW;
  int y = cell / FW;
  int si = a % 3, ri = a / 3;
  float s = (si==0) ? 8.f : ((si==1) ? 16.f : 32.f);
  float r = (ri==0) ? 0.5f : ((ri==1) ? 1.0f : 2.0f);
  float aw = s * sqrtf(1.0f / r);
  float ah = s * sqrtf(r);
  float gx = (float)x * 16.f, gy = (float)y * 16.f;
  float x1d = gx - 0.5f*aw, x2d = gx + 0.5f*aw;
  float y1d = gy - 0.5f*ah, y2d = gy + 0.5f*ah;
  float w = x2d - x1d, h = y2d - y1d;
  float cx = x1d + 0.5f*w, cy = y1d + 0.5f*h;
  float pcx = d.x*w + cx, pcy = d.y*h + cy;
  float pw = expf(d.z)*w, ph = expf(d.w)*h;
  float bx1 = fminf(fmaxf(pcx - 0.5f*pw, 0.f), W);
  float by1 = fminf(fmaxf(pcy - 0.5f*ph, 0.f), H);
  float bx2 = fminf(fmaxf(pcx + 0.5f*pw, 0.f), W);
  float by2 = fminf(fmaxf(pcy + 0.5f*ph, 0.f), H);
  return make_float4(bx1, by1, bx2, by2);
}

// ---------------------------------------------------------------------------
// Single fused kernel: one workgroup (1024 thr, 16 waves) per batch.
//  S0 zero hist(global)+slots(LDS) | S1 64K-bin hist + npos | S2 suffix scan
//  S3 scatter keys -> bin-ordered LDS slots | S4 exact rank -> perm[rank]=idx
//  S5 wave0: greedy NMS (LDS kept list, fused per-keep suppression) + output
// ---------------------------------------------------------------------------
__global__ void __launch_bounds__(1024) detect_kernel(
    const float* __restrict__ preds, const float4* __restrict__ regs4,
    const int* __restrict__ ih, const int* __restrict__ iw,
    u32* __restrict__ hist, u32* __restrict__ suffix, u32* __restrict__ cursor,
    float4* __restrict__ out)
{
  __shared__ float4 kbox[KEEP_POST + 4];   // kept boxes (NMS)
  __shared__ u64 slots[SLOTCAP];           // bin-ordered keys
  __shared__ u32 perm[KEEP_PRE + 16];      // rank -> element index
  __shared__ u32 psum[1024];
  __shared__ u32 warr[16];
  __shared__ u32 nposs;

  const int b = blockIdx.x;
  const int t = threadIdx.x;
  u32* histb = hist + (size_t)b*NBINS;
  u32* sufb  = suffix + (size_t)b*NBINS;
  u32* curb  = cursor + (size_t)b*NBINS;
  const float* pb = preds + b*NPRED;
  const float4* rb = regs4 + b*NPRED;
  const float W = (float)(*iw), H = (float)(*ih);

  // ---- S0: zero hist (64 bins/thread) + LDS slots -------------------------
  {
    uint4 z4 = make_uint4(0,0,0,0);
    uint4* hb4 = (uint4*)histb;
    #pragma unroll
    for (int q = 0; q < 16; ++q) hb4[t*16 + q] = z4;
    #pragma unroll
    for (int q = 0; q < 8; ++q) slots[q*1024 + t] = 0ull;
  }
  __syncthreads();

  // ---- S1: histogram build + npos (ballot per chunk, no divergence) -------
  {
    u32 mypos = 0;
    for (int c = 0; c < NCHUNK; ++c) {
      int n = c*1024 + t;
      bool valid = n < NPRED;
      float p = valid ? pb[n] : -1.0f;
      u64 bm = __ballot(valid && (p > 0.0f));
      mypos += (u32)__popcll(bm);          // uniform within the wave
      if (valid) {
        u32 u = __float_as_uint(p);
        u32 m = (u & 0x80000000u) ? ~u : (u | 0x80000000u);  // order-preserving
        atomicAdd(&histb[m >> 16], 1u);
      }
    }
    if ((t & 63) == 0) warr[t >> 6] = mypos;
  }
  __syncthreads();

  // ---- S2: suffix scan over 65536 bins (suffix[v] = count in bins > v) ----
  {
    const uint4* hb4 = (const uint4*)histb;
    u32 mysum = 0;
    #pragma unroll
    for (int q = 0; q < 16; ++q) {
      uint4 h = hb4[t*16 + q];
      mysum += h.x + h.y + h.z + h.w;
    }
    psum[t] = mysum;
    __syncthreads();
    for (int off = 1; off < 1024; off <<= 1) {
      u32 add = (t + off < 1024) ? psum[t + off] : 0;
      __syncthreads();
      psum[t] += add;
      __syncthreads();
    }
    u32 acc = psum[t] - mysum;             // sum over threads > t
    uint4* sb4 = (uint4*)sufb;
    uint4* cb4 = (uint4*)curb;
    #pragma unroll
    for (int q = 15; q >= 0; --q) {        // stream high->low within chunk
      uint4 h = hb4[t*16 + q];
      uint4 sv;
      sv.w = acc;
      sv.z = acc + h.w;
      sv.y = sv.z + h.z;
      sv.x = sv.y + h.y;
      sb4[t*16 + q] = sv;
      cb4[t*16 + q] = sv;                  // cursor starts at suffix
      acc = sv.x + h.x;
    }
    if (t == 0) { u32 s = 0; for (int wv = 0; wv < 16; ++wv) s += warr[wv]; nposs = s; }
  }
  __syncthreads();

  // ---- S3: scatter keys into bin-ordered LDS slots ------------------------
  // Gate on suffix<SLOTCAP: with 64K bins max bin ~25, any dropped element
  // has rank >= 6000 (base >= SLOTCAP - binsize > 6000).
  for (int c = 0; c < NCHUNK; ++c) {
    int n = c*1024 + t;
    if (n >= NPRED) break;
    float p = pb[n];
    u32 u = __float_as_uint(p);
    u32 m = (u & 0x80000000u) ? ~u : (u | 0x80000000u);
    u32 bin = m >> 16;
    if (sufb[bin] < SLOTCAP) {
      u32 pos = atomicAdd(&curb[bin], 1u);
      if (pos < SLOTCAP) slots[pos] = ((u64)m << 32) | (u32)(~(u32)n);
    }
  }
  __syncthreads();

  // ---- S4: exact rank = bin base + in-bin count of larger keys ------------
  #pragma unroll
  for (int q = 0; q < 8; ++q) {
    int i = q*1024 + t;
    u64 k = slots[i];
    if (k == 0) continue;                  // unwritten slot
    u32 bin = (u32)(k >> 48);
    u32 base = sufb[bin];
    if (base >= KEEP_PRE) continue;        // rank >= base >= 6000
    u32 cntb = histb[bin];
    u32 end = base + cntb; if (end > SLOTCAP) end = SLOTCAP;
    u32 r = base;
    for (u32 j = base; j < end; ++j) r += (slots[j] > k) ? 1u : 0u;
    if (r < KEEP_PRE) perm[r] = ~(u32)k;   // element index
  }
  __syncthreads();

  // ---- S5: greedy NMS + output, wave 0 only (no barriers past this point) -
  if (t >= 64) return;
  const int lane = t;
  const int npos = (int)nposs;
  float4* ob = out + b*KEEP_POST;
  const float4 zero = make_float4(0.f, 0.f, 0.f, 0.f);

  float4 cur; float carea;
  {
    u32 idx = perm[lane];
    float4 d = rb[idx];
    cur = decode_box(idx, d, W, H);
    carea = fmaxf(cur.z - cur.x, 0.f) * fmaxf(cur.w - cur.y, 0.f);
  }
  int cnt = 0;

  for (int blk = 0; blk < NBLK && cnt < KEEP_POST; ++blk) {
    const int base = blk * 64;
    // prefetch next block: perm read + regs gather (decode deferred)
    int nr_ = base + 64 + lane;
    u32 nidx = (nr_ < KEEP_PRE) ? perm[nr_] : 0u;
    float4 nd = rb[nidx];

    // ensure lane0's kbox ds_writes from previous closure are complete
    asm volatile("s_waitcnt lgkmcnt(0)" ::: "memory");

    // Phase A: my candidate vs all kept so far (uniform LDS broadcast, x8)
    int dead = 0;
    {
      int k = 0;
      for (; k + 8 <= cnt; k += 8) {
        float4 b0 = kbox[k+0], b1 = kbox[k+1], b2 = kbox[k+2], b3 = kbox[k+3];
        float4 b4 = kbox[k+4], b5 = kbox[k+5], b6 = kbox[k+6], b7 = kbox[k+7];
        dead |= (int)iou_sup_box(b0, cur, carea);
        dead |= (int)iou_sup_box(b1, cur, carea);
        dead |= (int)iou_sup_box(b2, cur, carea);
        dead |= (int)iou_sup_box(b3, cur, carea);
        dead |= (int)iou_sup_box(b4, cur, carea);
        dead |= (int)iou_sup_box(b5, cur, carea);
        dead |= (int)iou_sup_box(b6, cur, carea);
        dead |= (int)iou_sup_box(b7, cur, carea);
      }
      for (; k < cnt; ++k) dead |= (int)iou_sup_box(kbox[k], cur, carea);
    }
    bool alive = ((base + lane) < KEEP_PRE) && !dead;
    u64 A = __ballot((int)alive);

    // Fused closure: per actual keep, broadcast test clears its victims.
    while (A && cnt < KEEP_POST) {
      int j = (int)__builtin_ctzll(A);
      A &= A - 1;
      float jx1 = bcast(cur.x, j), jy1 = bcast(cur.y, j);
      float jx2 = bcast(cur.z, j), jy2 = bcast(cur.w, j);
      float ja  = bcast(carea, j);
      bool sup = iou_sup(jx1, jy1, jx2, jy2, ja,
                         cur.x, cur.y, cur.z, cur.w, carea);
      u64 S = __ballot((int)sup);
      A &= ~S;
      if (lane == 0) {
        float4 bj = make_float4(jx1, jy1, jx2, jy2);
        kbox[cnt] = bj;
        ob[cnt] = ((base + j) < npos) ? bj : zero;  // conf: rank < npos
      }
      ++cnt;
    }

    // decode next block's candidate (gather already in flight)
    cur = decode_box(nidx, nd, W, H);
    carea = fmaxf(cur.z - cur.x, 0.f) * fmaxf(cur.w - cur.y, 0.f);
  }
  // zero-fill tail rows (d_out poisoned before every timed launch)
  for (int k2 = cnt + lane; k2 < KEEP_POST; k2 += 64) ob[k2] = zero;
}

extern "C" void kernel_launch(void* const* d_in, const int* in_sizes, int n_in,
                              void* d_out, int out_size, void* d_ws, size_t ws_size,
                              hipStream_t stream) {
  const float* preds  = (const float*)d_in[0];
  const float4* regs4 = (const float4*)d_in[1];
  const int* ih       = (const int*)d_in[2];
  const int* iw       = (const int*)d_in[3];

  if (ws_size < (size_t)WS_NEEDED) return;  // loud failure (poisoned out)

  char* ws = (char*)d_ws;
  u32* hist   = (u32*)(ws + OFF_HIST);
  u32* suffix = (u32*)(ws + OFF_SUFFIX);
  u32* cursor = (u32*)(ws + OFF_CURSOR);

  detect_kernel<<<dim3(BS), 1024, 0, stream>>>(
      preds, regs4, ih, iw, hist, suffix, cursor, (float4*)d_out);
}

// Round 5
// 275.699 us; speedup vs baseline: 1.1437x; 1.1437x over previous
//
#include <hip/hip_runtime.h>
#include <stdint.h>

typedef unsigned long long u64;
typedef unsigned int u32;

#define FH 37
#define FW 62
#define NA 9
#define NPRED (FH*FW*NA)   // 20646
#define BS 4
#define KEEP_PRE 6000
#define KEEP_POST 300
#define NBINS 4096         // 12-bit bins: sign + 8-bit exp + 3 mantissa bits
#define SELCAP 3072        // ranks resolved per tranche
#define SLOTN 4096
#define NCHUNK 21          // ceil(20646/1024)

// ---------------------------------------------------------------------------
// helpers
// ---------------------------------------------------------------------------
__device__ __forceinline__ float bcast(float v, int srcLane) {
  return __int_as_float(__builtin_amdgcn_readlane(__float_as_int(v), srcLane));
}

// suppression test: kept box (k) vs candidate (c). Same op structure as the
// validated rounds 0-4 kernels (absmax=0).
__device__ __forceinline__ bool iou_sup(float kx1, float ky1, float kx2, float ky2,
                                        float ka, float cx1, float cy1,
                                        float cx2, float cy2, float ca) {
  float wx = fmaxf(fminf(kx2, cx2) - fmaxf(kx1, cx1), 0.f);
  float wy = fmaxf(fminf(ky2, cy2) - fmaxf(ky1, cy1), 0.f);
  float inter = wx * wy;
  float un = ka + ca - inter;
  return inter > 0.7f * fmaxf(un, 1e-9f);
}

// box decode — textually identical formula to rounds 0-4 (absmax=0).
__device__ __forceinline__ float4 decode_box(u32 n, float4 d, float W, float H) {
  int a = (int)(n % NA);
  int cell = (int)(n / NA);
  int x = cell % FW;
  int y = cell / FW;
  int si = a % 3, ri = a / 3;
  float s = (si==0) ? 8.f : ((si==1) ? 16.f : 32.f);
  float r = (ri==0) ? 0.5f : ((ri==1) ? 1.0f : 2.0f);
  float aw = s * sqrtf(1.0f / r);
  float ah = s * sqrtf(r);
  float gx = (float)x * 16.f, gy = (float)y * 16.f;
  float x1d = gx - 0.5f*aw, x2d = gx + 0.5f*aw;
  float y1d = gy - 0.5f*ah, y2d = gy + 0.5f*ah;
  float w = x2d - x1d, h = y2d - y1d;
  float cx = x1d + 0.5f*w, cy = y1d + 0.5f*h;
  float pcx = d.x*w + cx, pcy = d.y*h + cy;
  float pw = expf(d.z)*w, ph = expf(d.w)*h;
  float bx1 = fminf(fmaxf(pcx - 0.5f*pw, 0.f), W);
  float by1 = fminf(fmaxf(pcy - 0.5f*ph, 0.f), H);
  float bx2 = fminf(fmaxf(pcx + 0.5f*pw, 0.f), W);
  float by2 = fminf(fmaxf(pcy + 0.5f*ph, 0.f), H);
  return make_float4(bx1, by1, bx2, by2);
}

// ---------------------------------------------------------------------------
// Single fused kernel, ALL sort state in LDS. One WG (1024 thr) per batch.
//  S1 preds -> 21 regs/thread; 4096-bin LDS hist + npos
//  S2 shuffle-based suffix scan over bins (3 barriers)
//  per tranche (window of 3072 ranks; tranche 1 runs only if NMS starves):
//    S3 scatter keys of window-intersecting bins into LDS slots (SOFF-rebased)
//    S4 exact rank = bin suffix + in-bin larger-count -> perm[local rank]
//    S5 wave0: greedy NMS (LDS kept list + areas, fused per-keep closure)
// ---------------------------------------------------------------------------
__global__ void __launch_bounds__(1024) detect_kernel(
    const float* __restrict__ preds, const float4* __restrict__ regs4,
    const int* __restrict__ ih, const int* __restrict__ iw,
    float4* __restrict__ out)
{
  __shared__ u32 histL[NBINS];
  __shared__ u32 sufL[NBINS];
  __shared__ u32 curL[NBINS];
  __shared__ u64 slots[SLOTN];
  __shared__ u32 perm[SELCAP];
  __shared__ float4 kbox[KEEP_POST];
  __shared__ float  karea[KEEP_POST];
  __shared__ u32 wsum[16];
  __shared__ u32 wpos[16];
  __shared__ u32 SOFFs;
  __shared__ int  cntSh;
  __shared__ u32 nposSh;

  const int b = blockIdx.x;
  const int t = threadIdx.x;
  const int lane = t & 63;
  const int wv = t >> 6;
  const float* pb = preds + b*NPRED;
  const float4* rb = regs4 + b*NPRED;
  const float W = (float)(*iw), H = (float)(*ih);

  #pragma unroll
  for (int q = 0; q < 4; ++q) histL[q*1024 + t] = 0;
  if (t == 0) cntSh = 0;
  __syncthreads();

  // ---- S1: preds -> registers (read once), histogram + npos ---------------
  float pv[NCHUNK];
  #pragma unroll
  for (int c = 0; c < NCHUNK; ++c) {
    int n = c*1024 + t;
    pv[c] = (n < NPRED) ? pb[n] : -__builtin_inff();
  }
  u32 mypos = 0;
  #pragma unroll
  for (int c = 0; c < NCHUNK; ++c) {
    int n = c*1024 + t;
    bool valid = (n < NPRED);
    u64 bm = __ballot(valid && (pv[c] > 0.0f));
    mypos += (u32)__popcll(bm);
    u32 u = __float_as_uint(pv[c]);
    u32 m = (u & 0x80000000u) ? ~u : (u | 0x80000000u);  // order-preserving map
    if (valid) atomicAdd(&histL[m >> 20], 1u);
  }
  if (lane == 0) wpos[wv] = mypos;
  __syncthreads();

  // ---- S2: suffix scan (count of elements in strictly higher bins) -------
  {
    u32 h0 = histL[4*t], h1 = histL[4*t+1], h2 = histL[4*t+2], h3 = histL[4*t+3];
    u32 s = h0 + h1 + h2 + h3;
    u32 suf = s;                         // becomes inclusive in-wave suffix
    #pragma unroll
    for (int off = 1; off < 64; off <<= 1) {
      u32 o = __shfl_down(suf, off, 64);
      if (lane + off < 64) suf += o;
    }
    if (lane == 0) wsum[wv] = suf;       // wave total (lane0's suffix)
    __syncthreads();
    u32 hi = 0;
    for (int w2 = wv + 1; w2 < 16; ++w2) hi += wsum[w2];
    u32 St = hi + (suf - s);             // strictly-higher-thread total
    u32 s3 = St, s2 = s3 + h3, s1 = s2 + h2, s0 = s1 + h1;
    sufL[4*t] = s0; sufL[4*t+1] = s1; sufL[4*t+2] = s2; sufL[4*t+3] = s3;
    if (t == 0) {
      u32 np = 0;
      #pragma unroll
      for (int w2 = 0; w2 < 16; ++w2) np += wpos[w2];
      nposSh = np;
    }
  }
  __syncthreads();

  // ---- tranche loop (tranche 1 expected to never run on this data) -------
  #pragma unroll 1
  for (int tr = 0; tr < 2; ++tr) {
    const u32 winStart = (u32)tr * SELCAP;
    const u32 winEnd = winStart + SELCAP;
    const int rowLimit = (KEEP_PRE - (int)winStart < (int)SELCAP)
                           ? (KEEP_PRE - (int)winStart) : (int)SELCAP;

    #pragma unroll
    for (int q = 0; q < 4; ++q) slots[q*1024 + t] = 0ull;
    if (t == 0) SOFFs = 0xFFFFFFFFu;
    __syncthreads();

    // SOFF = min suffix among bins intersecting the window
    #pragma unroll
    for (int q = 0; q < 4; ++q) {
      int v = 4*t + q;
      u32 sv = sufL[v], hv = histL[v];
      if (hv && sv < winEnd && sv + hv > winStart) atomicMin(&SOFFs, sv);
    }
    __syncthreads();
    const u32 SOFF = SOFFs;

    #pragma unroll
    for (int q = 0; q < 4; ++q) {
      int v = 4*t + q;
      curL[v] = sufL[v] - SOFF;          // slot base (garbage for excluded bins)
    }
    __syncthreads();

    // ---- S3: scatter keys of included bins into slots ---------------------
    #pragma unroll
    for (int c = 0; c < NCHUNK; ++c) {
      int n = c*1024 + t;
      if (n < NPRED) {
        u32 u = __float_as_uint(pv[c]);
        u32 m = (u & 0x80000000u) ? ~u : (u | 0x80000000u);
        u32 bin = m >> 20;
        u32 sv = sufL[bin], hv = histL[bin];
        if (sv < winEnd && sv + hv > winStart) {
          u32 pos = atomicAdd(&curL[bin], 1u);
          if (pos < SLOTN) slots[pos] = ((u64)m << 32) | (u32)(~(u32)n);
        }
      }
    }
    __syncthreads();

    // ---- S4: exact rank -> perm[local rank] -------------------------------
    #pragma unroll
    for (int q = 0; q < 4; ++q) {
      int i = q*1024 + t;
      u64 k = slots[i];
      if (k != 0) {
        u32 bin = (u32)(k >> 52);
        u32 base = sufL[bin] - SOFF;
        u32 end = base + histL[bin]; if (end > SLOTN) end = SLOTN;
        u32 c2 = 0;
        for (u32 j = base; j < end; ++j) c2 += (slots[j] > k) ? 1u : 0u;
        int localr = (int)(sufL[bin] + c2) - (int)winStart;
        if (localr >= 0 && localr < rowLimit) perm[localr] = ~(u32)k;
      }
    }
    __syncthreads();

    // ---- S5: greedy NMS on wave 0 (no barriers inside) --------------------
    if (wv == 0) {
      int cnt = cntSh;
      const int npos = (int)nposSh;
      float4* ob = out + b*KEEP_POST;
      const float4 zero = make_float4(0.f, 0.f, 0.f, 0.f);
      const int nblk = (rowLimit + 63) >> 6;

      u32 idx0 = (lane < rowLimit) ? perm[lane] : perm[0];
      float4 d0 = rb[idx0];
      float4 cur = decode_box(idx0, d0, W, H);
      float carea = (cur.z - cur.x) * (cur.w - cur.y);  // == clamped (x2>=x1)

      for (int blk = 0; blk < nblk && cnt < KEEP_POST; ++blk) {
        const int base = blk * 64;
        int nr = base + 64 + lane;
        u32 nidx = (nr < rowLimit) ? perm[nr] : perm[0];
        float4 nd = rb[nidx];            // prefetch gather for next block

        // drain lane0's kbox/karea ds_writes from previous closure
        asm volatile("s_waitcnt lgkmcnt(0)" ::: "memory");

        // Phase A: my candidate vs all kept so far (uniform LDS broadcast)
        int dead = 0;
        {
          int k = 0;
          for (; k + 8 <= cnt; k += 8) {
            float4 b0 = kbox[k+0], b1 = kbox[k+1], b2 = kbox[k+2], b3 = kbox[k+3];
            float4 b4 = kbox[k+4], b5 = kbox[k+5], b6 = kbox[k+6], b7 = kbox[k+7];
            float a0 = karea[k+0], a1 = karea[k+1], a2 = karea[k+2], a3 = karea[k+3];
            float a4 = karea[k+4], a5 = karea[k+5], a6 = karea[k+6], a7 = karea[k+7];
            dead |= (int)iou_sup(b0.x,b0.y,b0.z,b0.w,a0, cur.x,cur.y,cur.z,cur.w,carea);
            dead |= (int)iou_sup(b1.x,b1.y,b1.z,b1.w,a1, cur.x,cur.y,cur.z,cur.w,carea);
            dead |= (int)iou_sup(b2.x,b2.y,b2.z,b2.w,a2, cur.x,cur.y,cur.z,cur.w,carea);
            dead |= (int)iou_sup(b3.x,b3.y,b3.z,b3.w,a3, cur.x,cur.y,cur.z,cur.w,carea);
            dead |= (int)iou_sup(b4.x,b4.y,b4.z,b4.w,a4, cur.x,cur.y,cur.z,cur.w,carea);
            dead |= (int)iou_sup(b5.x,b5.y,b5.z,b5.w,a5, cur.x,cur.y,cur.z,cur.w,carea);
            dead |= (int)iou_sup(b6.x,b6.y,b6.z,b6.w,a6, cur.x,cur.y,cur.z,cur.w,carea);
            dead |= (int)iou_sup(b7.x,b7.y,b7.z,b7.w,a7, cur.x,cur.y,cur.z,cur.w,carea);
          }
          for (; k < cnt; ++k) {
            float4 kb = kbox[k];
            dead |= (int)iou_sup(kb.x,kb.y,kb.z,kb.w,karea[k],
                                 cur.x,cur.y,cur.z,cur.w,carea);
          }
        }
        bool alive = ((base + lane) < rowLimit) && !dead;
        u64 A = __ballot((int)alive);

        // fused closure: per actual keep, broadcast test clears its victims
        while (A && cnt < KEEP_POST) {
          int j = (int)__builtin_ctzll(A);
          A &= A - 1;
          float jx1 = bcast(cur.x, j), jy1 = bcast(cur.y, j);
          float jx2 = bcast(cur.z, j), jy2 = bcast(cur.w, j);
          float ja  = bcast(carea, j);
          bool sup = iou_sup(jx1, jy1, jx2, jy2, ja,
                             cur.x, cur.y, cur.z, cur.w, carea);
          u64 S = __ballot((int)sup);
          A &= ~S;
          if (lane == 0) {
            float4 bj = make_float4(jx1, jy1, jx2, jy2);
            kbox[cnt] = bj;
            karea[cnt] = ja;
            ob[cnt] = ((int)(winStart + (u32)(base + j)) < npos) ? bj : zero;
          }
          ++cnt;
        }

        cur = decode_box(nidx, nd, W, H);
        carea = (cur.z - cur.x) * (cur.w - cur.y);
      }
      if (lane == 0) cntSh = cnt;
    }
    __syncthreads();
    if (cntSh >= KEEP_POST) break;
  }

  // ---- tail zero-fill (d_out is poisoned before every timed launch) ------
  if (wv == 0) {
    float4* ob = out + b*KEEP_POST;
    const float4 zero = make_float4(0.f, 0.f, 0.f, 0.f);
    for (int k2 = cntSh + lane; k2 < KEEP_POST; k2 += 64) ob[k2] = zero;
  }
}

extern "C" void kernel_launch(void* const* d_in, const int* in_sizes, int n_in,
                              void* d_out, int out_size, void* d_ws, size_t ws_size,
                              hipStream_t stream) {
  const float* preds  = (const float*)d_in[0];
  const float4* regs4 = (const float4*)d_in[1];
  const int* ih       = (const int*)d_in[2];
  const int* iw       = (const int*)d_in[3];
  (void)d_ws; (void)ws_size; (void)in_sizes; (void)n_in; (void)out_size;

  detect_kernel<<<dim3(BS), 1024, 0, stream>>>(
      preds, regs4, ih, iw, (float4*)d_out);
}

// Round 6
// 200.571 us; speedup vs baseline: 1.5721x; 1.3746x over previous
//
#include <hip/hip_runtime.h>
#include <stdint.h>

typedef unsigned long long u64;
typedef unsigned int u32;

#define FH 37
#define FW 62
#define NA 9
#define NPRED 20646        // FH*FW*NA
#define BS 4
#define KEEP_PRE 6000
#define KEEP_POST 300
#define NBINS 4096         // coarse: sign + 8-bit exp + 3 mantissa bits
#define SELCAP 3072        // ranks resolved per tranche
#define SLOTN 6144
#define FB_BASE 4608       // slots [FB_BASE, SLOTN) reserved for fallback bins
#define NFB 640
#define NCHUNK 21          // ceil(20646/1024)
#define FSLOTS 32          // coarse bins covered by the fine map
#define FSUB 128           // fine sub-bins per coarse bin (bits [13:20))

// ---- LDS layout (bytes). cbox overlays fineH/fineSuf/fineCur (dead after S4).
#define L_HIST   0u        // 4096 u32   coarse hist            (lives whole kernel)
#define L_SUF    16384u    // 4096 u32   coarse suffix          (lives whole kernel)
#define L_FINEH  32768u    // 4096 u32   fine hist
#define L_FINES  49152u    // 4096 u32   fine suffix (pristine)
#define L_FINEC  65536u    // 4096 u32   fine cursor
#define L_FBCUR  81920u    // 640 u32    fallback-bin cursors
#define L_SLOTS  84480u    // 6144 u64
#define L_PERM   133632u   // 3072 u32   rank -> element index
#define L_KBOX   145920u   // 300 float4 kept boxes
#define L_KAREA  150720u   // 300 f32    kept areas
#define L_WSUM   151920u   // 16 u32
#define L_WPOS   151984u   // 16 u32
#define L_SCAL   152048u   // binLo, binHi, cnt, npos
#define LDS_TOTAL 152064u
#define L_CBOX   32768u    // 3072 float4 == exactly fineH+fineSuf+fineC region

// ---------------------------------------------------------------------------
__device__ __forceinline__ u32 mapbits(float p) {
  u32 u = __float_as_uint(p);
  return (u & 0x80000000u) ? ~u : (u | 0x80000000u);   // order-preserving map
}
__device__ __forceinline__ float bcast(float v, int srcLane) {
  return __int_as_float(__builtin_amdgcn_readlane(__float_as_int(v), srcLane));
}
// suppression test — textually identical op structure to rounds 0-5 (absmax=0)
__device__ __forceinline__ bool iou_sup(float kx1, float ky1, float kx2, float ky2,
                                        float ka, float cx1, float cy1,
                                        float cx2, float cy2, float ca) {
  float wx = fmaxf(fminf(kx2, cx2) - fmaxf(kx1, cx1), 0.f);
  float wy = fmaxf(fminf(ky2, cy2) - fmaxf(ky1, cy1), 0.f);
  float inter = wx * wy;
  float un = ka + ca - inter;
  return inter > 0.7f * fmaxf(un, 1e-9f);
}
// box decode — textually identical formula to rounds 0-5 (absmax=0)
__device__ __forceinline__ float4 decode_box(u32 n, float4 d, float W, float H) {
  int a = (int)(n % NA);
  int cell = (int)(n / NA);
  int x = cell % FW;
  int y = cell / FW;
  int si = a % 3, ri = a / 3;
  float s = (si==0) ? 8.f : ((si==1) ? 16.f : 32.f);
  float r = (ri==0) ? 0.5f : ((ri==1) ? 1.0f : 2.0f);
  float aw = s * sqrtf(1.0f / r);
  float ah = s * sqrtf(r);
  float gx = (float)x * 16.f, gy = (float)y * 16.f;
  float x1d = gx - 0.5f*aw, x2d = gx + 0.5f*aw;
  float y1d = gy - 0.5f*ah, y2d = gy + 0.5f*ah;
  float w = x2d - x1d, h = y2d - y1d;
  float cx = x1d + 0.5f*w, cy = y1d + 0.5f*h;
  float pcx = d.x*w + cx, pcy = d.y*h + cy;
  float pw = expf(d.z)*w, ph = expf(d.w)*h;
  float bx1 = fminf(fmaxf(pcx - 0.5f*pw, 0.f), W);
  float by1 = fminf(fmaxf(pcy - 0.5f*ph, 0.f), H);
  float bx2 = fminf(fmaxf(pcx + 0.5f*pw, 0.f), W);
  float by2 = fminf(fmaxf(pcy + 0.5f*ph, 0.f), H);
  return make_float4(bx1, by1, bx2, by2);
}

// 4096-bin suffix scan (count of elements in strictly-higher bins).
// Contains one barrier; caller must barrier before consuming suf from others.
__device__ __forceinline__ void suffix_scan4096(const u32* h, u32* suf, u32* cur,
                                                u32* wsum, int t, int lane, int wv) {
  u32 h0 = h[4*t], h1 = h[4*t+1], h2 = h[4*t+2], h3 = h[4*t+3];
  u32 s = h0 + h1 + h2 + h3;
  u32 sf = s;
  #pragma unroll
  for (int off = 1; off < 64; off <<= 1) {
    u32 o = __shfl_down(sf, off, 64);
    if (lane + off < 64) sf += o;
  }
  if (lane == 0) wsum[wv] = sf;
  __syncthreads();
  u32 hi = 0;
  for (int w2 = wv + 1; w2 < 16; ++w2) hi += wsum[w2];
  u32 St = hi + (sf - s);
  u32 s3 = St, s2 = s3 + h3, s1 = s2 + h2, s0 = s1 + h1;
  suf[4*t] = s0; suf[4*t+1] = s1; suf[4*t+2] = s2; suf[4*t+3] = s3;
  if (cur) { cur[4*t] = s0; cur[4*t+1] = s1; cur[4*t+2] = s2; cur[4*t+3] = s3; }
}

// ---------------------------------------------------------------------------
// Fused kernel, one WG (1024 thr) per batch, all sort state in LDS.
//  S1 preds->regs, coarse hist, npos | S2 coarse suffix scan
//  per tranche: window bins [binLo,binHi]; fine re-bin top-32 coarse bins by
//  7 more mantissa bits -> max fine bin ~10 -> exact rank scan is trivial;
//  coarse bins below cBase (empty for Gaussian) use exact coarse-scan fallback.
//  Then 1024-thread box pre-decode into LDS cbox, then wave-0 greedy NMS.
// ---------------------------------------------------------------------------
__global__ void __launch_bounds__(1024, 4) detect_kernel(
    const float* __restrict__ preds, const float4* __restrict__ regs4,
    const int* __restrict__ ih, const int* __restrict__ iw,
    float4* __restrict__ out)
{
  __shared__ __align__(16) char smem[LDS_TOTAL];
  u32*    histL   = (u32*)(smem + L_HIST);
  u32*    sufL    = (u32*)(smem + L_SUF);
  u32*    fineH   = (u32*)(smem + L_FINEH);
  u32*    fineSuf = (u32*)(smem + L_FINES);
  u32*    fineCur = (u32*)(smem + L_FINEC);
  u32*    fbCur   = (u32*)(smem + L_FBCUR);
  u64*    slots   = (u64*)(smem + L_SLOTS);
  u32*    perm    = (u32*)(smem + L_PERM);
  float4* kbox    = (float4*)(smem + L_KBOX);
  float*  karea   = (float*)(smem + L_KAREA);
  u32*    wsum    = (u32*)(smem + L_WSUM);
  u32*    wpos    = (u32*)(smem + L_WPOS);
  u32*    scal    = (u32*)(smem + L_SCAL);   // 0:binLo 1:binHi 2:cnt 3:npos
  float4* cbox    = (float4*)(smem + L_CBOX);

  const int b = blockIdx.x;
  const int t = threadIdx.x;
  const int lane = t & 63;
  const int wv = t >> 6;
  const float* pb = preds + b*NPRED;
  const float4* rb = regs4 + b*NPRED;
  const float W = (float)(*iw), H = (float)(*ih);

  #pragma unroll
  for (int q = 0; q < 4; ++q) histL[q*1024 + t] = 0;
  if (t == 0) scal[2] = 0;
  __syncthreads();

  // ---- S1: preds -> registers (read once), coarse hist + npos -------------
  float pv[NCHUNK];
  #pragma unroll
  for (int c = 0; c < NCHUNK; ++c) {
    int n = c*1024 + t;
    pv[c] = (n < NPRED) ? pb[n] : -__builtin_inff();
  }
  {
    u32 mypos = 0;
    #pragma unroll
    for (int c = 0; c < NCHUNK; ++c) {
      int n = c*1024 + t;
      bool valid = (n < NPRED);
      u64 bm = __ballot(valid && (pv[c] > 0.0f));
      mypos += (u32)__popcll(bm);
      u32 m = mapbits(pv[c]);
      if (valid) atomicAdd(&histL[m >> 20], 1u);
    }
    if (lane == 0) wpos[wv] = mypos;
  }
  __syncthreads();

  // ---- S2: coarse suffix scan ---------------------------------------------
  suffix_scan4096(histL, sufL, nullptr, wsum, t, lane, wv);
  if (t == 0) {
    u32 np = 0;
    #pragma unroll
    for (int w2 = 0; w2 < 16; ++w2) np += wpos[w2];
    scal[3] = np;
  }
  __syncthreads();

  // ---- tranche loop (tranche 1 runs only if NMS starves before 300) ------
  #pragma unroll 1
  for (int tr = 0; tr < 2; ++tr) {
    const u32 winStart = (u32)tr * SELCAP;
    const u32 winEnd = winStart + SELCAP;
    const int rowLimit = (KEEP_PRE - (int)winStart < (int)SELCAP)
                           ? (KEEP_PRE - (int)winStart) : (int)SELCAP;

    if (t == 0) { scal[0] = 0xFFFFFFFFu; scal[1] = 0u; }
    __syncthreads();
    #pragma unroll
    for (int q = 0; q < 4; ++q) {
      int v = 4*t + q;
      u32 hv = histL[v], sv = sufL[v];
      if (hv && sv < winEnd && sv + hv > winStart) {
        atomicMin(&scal[0], (u32)v);
        atomicMax(&scal[1], (u32)v);
      }
    }
    __syncthreads();
    const u32 binLo = scal[0], binHi = scal[1];
    u32 cBase = binLo;
    if (binHi - binLo >= FSLOTS) cBase = binHi - (FSLOTS - 1);
    const u32 S_top = sufL[binHi];                 // # in coarse bins > binHi
    const u32 S_cb = (cBase > 0) ? sufL[cBase-1] : 0;  // # in bins >= cBase
    const u32 rebWinEnd = winEnd - S_top;

    #pragma unroll
    for (int q = 0; q < 4; ++q) fineH[q*1024 + t] = 0;
    #pragma unroll
    for (int q = 0; q < 6; ++q) slots[q*1024 + t] = 0ull;
    if (t < NFB) {
      u32 v = binLo + (u32)t;
      fbCur[t] = (v < cBase) ? (FB_BASE + (sufL[v] - S_cb)) : (u32)SLOTN;
    }
    __syncthreads();

    // ---- fine histogram over top-FSLOTS window coarse bins ----------------
    #pragma unroll
    for (int c = 0; c < NCHUNK; ++c) {
      int n = c*1024 + t;
      if (n < NPRED) {
        u32 m = mapbits(pv[c]);
        u32 cb = m >> 20;
        if (cb >= cBase && cb <= binHi)
          atomicAdd(&fineH[((cb - cBase) << 7) | ((m >> 13) & 0x7F)], 1u);
      }
    }
    __syncthreads();
    suffix_scan4096(fineH, fineSuf, fineCur, wsum, t, lane, wv);
    __syncthreads();

    // ---- scatter keys into slots (fine region + fallback region) ---------
    #pragma unroll
    for (int c = 0; c < NCHUNK; ++c) {
      int n = c*1024 + t;
      if (n < NPRED) {
        u32 m = mapbits(pv[c]);
        u32 cb = m >> 20;
        u64 key = ((u64)m << 32) | (u32)(~(u32)n);
        if (cb >= cBase && cb <= binHi) {
          u32 F = ((cb - cBase) << 7) | ((m >> 13) & 0x7F);
          if (fineSuf[F] < rebWinEnd) {
            u32 pos = atomicAdd(&fineCur[F], 1u);
            if (pos < FB_BASE) slots[pos] = key;
          }
        } else if (cb >= binLo && cb < cBase) {
          u32 fo = cb - binLo;
          if (fo < NFB) {
            u32 pos = atomicAdd(&fbCur[fo], 1u);
            if (pos < SLOTN) slots[pos] = key;
          }
        }
      }
    }
    __syncthreads();

    // ---- exact rank -> perm[local rank] -----------------------------------
    #pragma unroll
    for (int q = 0; q < 6; ++q) {
      int i = q*1024 + t;
      u64 k = slots[i];
      if (k != 0) {
        u32 m = (u32)(k >> 32);
        u32 cb = m >> 20;
        u32 rank;
        if (cb >= cBase) {
          u32 F = ((cb - cBase) << 7) | ((m >> 13) & 0x7F);
          u32 base = fineSuf[F];
          u32 end = base + fineH[F]; if (end > FB_BASE) end = FB_BASE;
          u32 c2 = 0;
          for (u32 j = base; j < end; ++j) c2 += (slots[j] > k) ? 1u : 0u;
          rank = S_top + fineSuf[F] + c2;
        } else {
          u32 base = FB_BASE + (sufL[cb] - S_cb);
          u32 end = base + histL[cb]; if (end > SLOTN) end = SLOTN;
          u32 c2 = 0;
          for (u32 j = base; j < end; ++j) c2 += (slots[j] > k) ? 1u : 0u;
          rank = sufL[cb] + c2;
        }
        int local = (int)rank - (int)winStart;
        if (local >= 0 && local < rowLimit) perm[local] = ~(u32)k;
      }
    }
    __syncthreads();

    // ---- parallel pre-decode of window boxes into LDS (overlays fine arrays)
    for (int r = t; r < rowLimit; r += 1024) {
      u32 idx = perm[r];
      float4 d = rb[idx];
      cbox[r] = decode_box(idx, d, W, H);
    }
    __syncthreads();

    // ---- greedy NMS on wave 0 (no barriers inside) ------------------------
    if (wv == 0) {
      int cnt = (int)scal[2];
      const int npos = (int)scal[3];
      float4* ob = out + b*KEEP_POST;
      const float4 zero = make_float4(0.f, 0.f, 0.f, 0.f);
      const int nblk = (rowLimit + 63) >> 6;

      for (int blk = 0; blk < nblk && cnt < KEEP_POST; ++blk) {
        const int base = blk * 64;
        const int ci = base + lane;
        float4 cur = cbox[(ci < rowLimit) ? ci : 0];
        float carea = (cur.z - cur.x) * (cur.w - cur.y);

        // drain lane0's kbox/karea ds_writes from previous closure
        asm volatile("s_waitcnt lgkmcnt(0)" ::: "memory");

        // Phase A: my candidate vs all kept so far (uniform LDS broadcast)
        int dead = 0;
        {
          int k = 0;
          for (; k + 8 <= cnt; k += 8) {
            float4 b0 = kbox[k+0], b1 = kbox[k+1], b2 = kbox[k+2], b3 = kbox[k+3];
            float4 b4 = kbox[k+4], b5 = kbox[k+5], b6 = kbox[k+6], b7 = kbox[k+7];
            float a0 = karea[k+0], a1 = karea[k+1], a2 = karea[k+2], a3 = karea[k+3];
            float a4 = karea[k+4], a5 = karea[k+5], a6 = karea[k+6], a7 = karea[k+7];
            dead |= (int)iou_sup(b0.x,b0.y,b0.z,b0.w,a0, cur.x,cur.y,cur.z,cur.w,carea);
            dead |= (int)iou_sup(b1.x,b1.y,b1.z,b1.w,a1, cur.x,cur.y,cur.z,cur.w,carea);
            dead |= (int)iou_sup(b2.x,b2.y,b2.z,b2.w,a2, cur.x,cur.y,cur.z,cur.w,carea);
            dead |= (int)iou_sup(b3.x,b3.y,b3.z,b3.w,a3, cur.x,cur.y,cur.z,cur.w,carea);
            dead |= (int)iou_sup(b4.x,b4.y,b4.z,b4.w,a4, cur.x,cur.y,cur.z,cur.w,carea);
            dead |= (int)iou_sup(b5.x,b5.y,b5.z,b5.w,a5, cur.x,cur.y,cur.z,cur.w,carea);
            dead |= (int)iou_sup(b6.x,b6.y,b6.z,b6.w,a6, cur.x,cur.y,cur.z,cur.w,carea);
            dead |= (int)iou_sup(b7.x,b7.y,b7.z,b7.w,a7, cur.x,cur.y,cur.z,cur.w,carea);
          }
          for (; k < cnt; ++k) {
            float4 kb = kbox[k];
            dead |= (int)iou_sup(kb.x,kb.y,kb.z,kb.w,karea[k],
                                 cur.x,cur.y,cur.z,cur.w,carea);
          }
        }
        bool alive = (ci < rowLimit) && !dead;
        u64 A = __ballot((int)alive);

        // fused closure: per actual keep, broadcast test clears its victims
        while (A && cnt < KEEP_POST) {
          int j = (int)__builtin_ctzll(A);
          A &= A - 1;
          float jx1 = bcast(cur.x, j), jy1 = bcast(cur.y, j);
          float jx2 = bcast(cur.z, j), jy2 = bcast(cur.w, j);
          float ja  = bcast(carea, j);
          bool sup = iou_sup(jx1, jy1, jx2, jy2, ja,
                             cur.x, cur.y, cur.z, cur.w, carea);
          u64 S = __ballot((int)sup);
          A &= ~S;
          if (lane == 0) {
            float4 bj = make_float4(jx1, jy1, jx2, jy2);
            kbox[cnt] = bj;
            karea[cnt] = ja;
            ob[cnt] = ((int)(winStart + (u32)(base + j)) < npos) ? bj : zero;
          }
          ++cnt;
        }
      }
      if (lane == 0) scal[2] = (u32)cnt;
    }
    __syncthreads();
    if ((int)scal[2] >= KEEP_POST) break;
  }

  // ---- tail zero-fill (d_out is poisoned before every timed launch) ------
  if (wv == 0) {
    float4* ob = out + b*KEEP_POST;
    const float4 zero = make_float4(0.f, 0.f, 0.f, 0.f);
    for (int k2 = (int)scal[2] + lane; k2 < KEEP_POST; k2 += 64) ob[k2] = zero;
  }
}

extern "C" void kernel_launch(void* const* d_in, const int* in_sizes, int n_in,
                              void* d_out, int out_size, void* d_ws, size_t ws_size,
                              hipStream_t stream) {
  const float* preds  = (const float*)d_in[0];
  const float4* regs4 = (const float4*)d_in[1];
  const int* ih       = (const int*)d_in[2];
  const int* iw       = (const int*)d_in[3];
  (void)d_ws; (void)ws_size; (void)in_sizes; (void)n_in; (void)out_size;

  detect_kernel<<<dim3(BS), 1024, 0, stream>>>(
      preds, regs4, ih, iw, (float4*)d_out);
}

// Round 7
// 171.991 us; speedup vs baseline: 1.8333x; 1.1662x over previous
//
#include <hip/hip_runtime.h>
#include <stdint.h>

typedef unsigned long long u64;
typedef unsigned int u32;

#define FH 37
#define FW 62
#define NA 9
#define NPRED 20646        // FH*FW*NA
#define BS 4
#define KEEP_PRE 6000
#define KEEP_POST 300
#define NBINS 4096         // coarse: sign + 8-bit exp + 3 mantissa bits
#define SELCAP 3072        // ranks resolved per tranche
#define SLOTN 6144
#define FB_BASE 4608       // slots [FB_BASE, SLOTN) = fallback-bin region
#define NFB 640
#define NCHUNK 21          // ceil(20646/1024)
#define FSLOTS 32          // coarse bins covered by the fine map
#define FSUB 64            // fine sub-bins per coarse bin (bits [14:20))
#define NFINE 2048         // FSLOTS*FSUB

// ---- LDS arena (bytes). Regions reused over time:
//  RG1: hist replicas (S1-S2) -> slots u64[6144] (T1-T5) -> cboxL float4[3072]
//  RG2: fineH/fineS/fineC (T1-T5) -> careaL f32[3072] (T6-)
#define L_HIST   0u        // u32[4096] coarse hist (merged)   persistent
#define L_SUF    16384u    // u32[4096] coarse suffix          persistent
#define L_RG1    32768u    // 48K
#define L_RG2    81920u    // 24K
#define L_FBCUR  106496u   // u32[640]
#define L_PERM   109056u   // u32[3072] rank -> element index
#define L_KBOX   121344u   // float4[304] kept boxes
#define L_KAREA  126208u   // f32[304]
#define L_WSUM   127424u   // u32[16]
#define L_WPOS   127488u   // u32[16]
#define L_SCAL   127552u   // 0:binLo 1:binHi 2:cnt 3:npos
#define L_AW     127616u   // u64[16] per-wave dead ballots
#define L_MROW   127744u   // u64[64] intra-block suppression rows
#define LDS_TOTAL 128256u

// ---------------------------------------------------------------------------
__device__ __forceinline__ u32 mapbits(float p) {
  u32 u = __float_as_uint(p);
  return (u & 0x80000000u) ? ~u : (u | 0x80000000u);   // order-preserving map
}
// suppression test — textually identical op structure to rounds 0-5 (absmax=0)
__device__ __forceinline__ bool iou_sup(float kx1, float ky1, float kx2, float ky2,
                                        float ka, float cx1, float cy1,
                                        float cx2, float cy2, float ca) {
  float wx = fmaxf(fminf(kx2, cx2) - fmaxf(kx1, cx1), 0.f);
  float wy = fmaxf(fminf(ky2, cy2) - fmaxf(ky1, cy1), 0.f);
  float inter = wx * wy;
  float un = ka + ca - inter;
  return inter > 0.7f * fmaxf(un, 1e-9f);
}
// box decode — textually identical formula to rounds 0-5 (absmax=0)
__device__ __forceinline__ float4 decode_box(u32 n, float4 d, float W, float H) {
  int a = (int)(n % NA);
  int cell = (int)(n / NA);
  int x = cell % FW;
  int y = cell / FW;
  int si = a % 3, ri = a / 3;
  float s = (si==0) ? 8.f : ((si==1) ? 16.f : 32.f);
  float r = (ri==0) ? 0.5f : ((ri==1) ? 1.0f : 2.0f);
  float aw = s * sqrtf(1.0f / r);
  float ah = s * sqrtf(r);
  float gx = (float)x * 16.f, gy = (float)y * 16.f;
  float x1d = gx - 0.5f*aw, x2d = gx + 0.5f*aw;
  float y1d = gy - 0.5f*ah, y2d = gy + 0.5f*ah;
  float w = x2d - x1d, h = y2d - y1d;
  float cx = x1d + 0.5f*w, cy = y1d + 0.5f*h;
  float pcx = d.x*w + cx, pcy = d.y*h + cy;
  float pw = expf(d.z)*w, ph = expf(d.w)*h;
  float bx1 = fminf(fmaxf(pcx - 0.5f*pw, 0.f), W);
  float by1 = fminf(fmaxf(pcy - 0.5f*ph, 0.f), H);
  float bx2 = fminf(fmaxf(pcx + 0.5f*pw, 0.f), W);
  float by2 = fminf(fmaxf(pcy + 0.5f*ph, 0.f), H);
  return make_float4(bx1, by1, bx2, by2);
}

// ---------------------------------------------------------------------------
// Fused kernel, one WG (1024 thr, 16 waves) per batch, all sort state in LDS.
// No register pred-cache (spill-proof): preds re-read per pass (L2-hot).
// NMS: 16-wave Phase A + parallel 64x64 intra-block mask + bit-sweep closure.
// ---------------------------------------------------------------------------
__global__ void __launch_bounds__(1024) detect_kernel(
    const float* __restrict__ preds, const float4* __restrict__ regs4,
    const int* __restrict__ ih, const int* __restrict__ iw,
    float4* __restrict__ out)
{
  __shared__ __align__(16) char smem[LDS_TOTAL];
  u32*    histL  = (u32*)(smem + L_HIST);
  u32*    sufL   = (u32*)(smem + L_SUF);
  u32*    repl   = (u32*)(smem + L_RG1);          // 3 x 4096 replicas
  u64*    slots  = (u64*)(smem + L_RG1);
  float4* cboxL  = (float4*)(smem + L_RG1);
  u32*    fineH  = (u32*)(smem + L_RG2);
  u32*    fineS  = (u32*)(smem + L_RG2 + 8192);
  u32*    fineC  = (u32*)(smem + L_RG2 + 16384);
  float*  careaL = (float*)(smem + L_RG2);
  u32*    fbCur  = (u32*)(smem + L_FBCUR);
  u32*    perm   = (u32*)(smem + L_PERM);
  float4* kbox   = (float4*)(smem + L_KBOX);
  float*  karea  = (float*)(smem + L_KAREA);
  u32*    wsum   = (u32*)(smem + L_WSUM);
  u32*    wpos   = (u32*)(smem + L_WPOS);
  u32*    scal   = (u32*)(smem + L_SCAL);
  u64*    aw     = (u64*)(smem + L_AW);
  u64*    mrow   = (u64*)(smem + L_MROW);

  const int b = blockIdx.x;
  const int t = threadIdx.x;
  const int lane = t & 63;
  const int wv = t >> 6;
  const float* pb = preds + b*NPRED;
  const float4* rb = regs4 + b*NPRED;
  const float W = (float)(*iw), H = (float)(*ih);
  float4* ob = out + b*KEEP_POST;
  const float4 zero = make_float4(0.f, 0.f, 0.f, 0.f);

  // ---- S0: zero hist + replicas (64KB = 16 u32/thread) --------------------
  #pragma unroll
  for (int q = 0; q < 4; ++q) histL[q*1024 + t] = 0;
  #pragma unroll
  for (int q = 0; q < 12; ++q) repl[q*1024 + t] = 0;
  if (t == 0) scal[2] = 0;
  __syncthreads();

  // ---- S1: coarse hist into per-wave-group replica + npos -----------------
  {
    u32* repA = ((wv & 3) == 0) ? histL : (repl + ((wv & 3) - 1) * 4096);
    u32 mypos = 0;
    #pragma unroll 4
    for (int c = 0; c < NCHUNK; ++c) {
      int n = c*1024 + t;
      bool valid = (n < NPRED);
      float p = valid ? pb[n] : -1.0f;
      u64 bm = __ballot(valid && (p > 0.0f));
      mypos += (u32)__popcll(bm);
      if (valid) atomicAdd(&repA[mapbits(p) >> 20], 1u);
    }
    if (lane == 0) wpos[wv] = mypos;
  }
  __syncthreads();

  // ---- S2: merge replicas + coarse suffix scan ----------------------------
  {
    u32* r2 = repl + 4096; u32* r3 = repl + 8192;
    u32 h0 = histL[4*t+0] + repl[4*t+0] + r2[4*t+0] + r3[4*t+0];
    u32 h1 = histL[4*t+1] + repl[4*t+1] + r2[4*t+1] + r3[4*t+1];
    u32 h2 = histL[4*t+2] + repl[4*t+2] + r2[4*t+2] + r3[4*t+2];
    u32 h3 = histL[4*t+3] + repl[4*t+3] + r2[4*t+3] + r3[4*t+3];
    histL[4*t+0]=h0; histL[4*t+1]=h1; histL[4*t+2]=h2; histL[4*t+3]=h3;
    u32 s = h0 + h1 + h2 + h3;
    u32 sf = s;
    #pragma unroll
    for (int off = 1; off < 64; off <<= 1) {
      u32 o = __shfl_down(sf, off, 64);
      if (lane + off < 64) sf += o;
    }
    if (lane == 0) wsum[wv] = sf;
    __syncthreads();
    u32 hi = 0;
    for (int w2 = wv + 1; w2 < 16; ++w2) hi += wsum[w2];
    u32 St = hi + (sf - s);
    u32 s3 = St, s2 = s3 + h3, s1 = s2 + h2, s0 = s1 + h1;
    sufL[4*t+0]=s0; sufL[4*t+1]=s1; sufL[4*t+2]=s2; sufL[4*t+3]=s3;
    if (t == 0) {
      u32 np = 0;
      #pragma unroll
      for (int w2 = 0; w2 < 16; ++w2) np += wpos[w2];
      scal[3] = np;
    }
  }
  __syncthreads();

  // ---- tranche loop (tranche 1 runs only if NMS starves before 300) ------
  #pragma unroll 1
  for (int tr = 0; tr < 2; ++tr) {
    const u32 winStart = (u32)tr * SELCAP;
    const u32 winEnd = winStart + SELCAP;
    const int rowLimit = (KEEP_PRE - (int)winStart < (int)SELCAP)
                           ? (KEEP_PRE - (int)winStart) : (int)SELCAP;

    if (t == 0) { scal[0] = 0xFFFFFFFFu; scal[1] = 0u; }
    __syncthreads();
    #pragma unroll
    for (int q = 0; q < 4; ++q) {
      int v = 4*t + q;
      u32 hv = histL[v], sv = sufL[v];
      if (hv && sv < winEnd && sv + hv > winStart) {
        atomicMin(&scal[0], (u32)v);
        atomicMax(&scal[1], (u32)v);
      }
    }
    __syncthreads();
    const u32 binLo = scal[0], binHi = scal[1];
    u32 cBase = binLo;
    if (binHi - binLo >= FSLOTS) cBase = binHi - (FSLOTS - 1);
    const u32 S_top = sufL[binHi];                     // # in coarse bins > binHi
    const u32 S_cb = (cBase > 0) ? sufL[cBase-1] : 0;  // # in bins >= cBase
    const u32 rebWinEnd = winEnd - S_top;

    // ---- T1: init fine arrays + slots + fallback cursors ------------------
    #pragma unroll
    for (int q = 0; q < 2; ++q) fineH[q*1024 + t] = 0;
    #pragma unroll
    for (int q = 0; q < 6; ++q) slots[q*1024 + t] = 0ull;
    if (t < NFB) {
      u32 v = binLo + (u32)t;
      fbCur[t] = (v < cBase) ? (FB_BASE + (sufL[v] - S_cb)) : (u32)SLOTN;
    }
    __syncthreads();

    // ---- T2: fine histogram over top-FSLOTS window coarse bins ------------
    #pragma unroll 4
    for (int c = 0; c < NCHUNK; ++c) {
      int n = c*1024 + t;
      if (n < NPRED) {
        u32 m = mapbits(pb[n]);
        u32 cb = m >> 20;
        if (cb >= cBase && cb <= binHi)
          atomicAdd(&fineH[((cb - cBase) << 6) | ((m >> 14) & 0x3F)], 1u);
      }
    }
    __syncthreads();

    // ---- T3: fine suffix scan (2048 bins, 2/thread) -----------------------
    {
      u32 f0 = fineH[2*t], f1 = fineH[2*t+1];
      u32 s = f0 + f1;
      u32 sf = s;
      #pragma unroll
      for (int off = 1; off < 64; off <<= 1) {
        u32 o = __shfl_down(sf, off, 64);
        if (lane + off < 64) sf += o;
      }
      if (lane == 0) wsum[wv] = sf;
      __syncthreads();
      u32 hi = 0;
      for (int w2 = wv + 1; w2 < 16; ++w2) hi += wsum[w2];
      u32 St = hi + (sf - s);
      u32 sA = St + f1, sB = St;
      fineS[2*t] = sA; fineS[2*t+1] = sB;
      fineC[2*t] = sA; fineC[2*t+1] = sB;
    }
    __syncthreads();

    // ---- T4: scatter keys into slots (fine region + fallback region) -----
    #pragma unroll 4
    for (int c = 0; c < NCHUNK; ++c) {
      int n = c*1024 + t;
      if (n < NPRED) {
        u32 m = mapbits(pb[n]);
        u32 cb = m >> 20;
        u64 key = ((u64)m << 32) | (u32)(~(u32)n);
        if (cb >= cBase && cb <= binHi) {
          u32 F = ((cb - cBase) << 6) | ((m >> 14) & 0x3F);
          if (fineS[F] < rebWinEnd) {
            u32 pos = atomicAdd(&fineC[F], 1u);
            if (pos < FB_BASE) slots[pos] = key;
          }
        } else if (cb >= binLo && cb < cBase) {
          u32 fo = cb - binLo;
          if (fo < NFB) {
            u32 pos = atomicAdd(&fbCur[fo], 1u);
            if (pos < SLOTN) slots[pos] = key;
          }
        }
      }
    }
    __syncthreads();

    // ---- T5: exact rank -> perm[local rank] -------------------------------
    #pragma unroll
    for (int q = 0; q < 6; ++q) {
      int i = q*1024 + t;
      u64 k = slots[i];
      if (k != 0) {
        u32 m = (u32)(k >> 32);
        u32 cb = m >> 20;
        u32 rank;
        if (cb >= cBase) {
          u32 F = ((cb - cBase) << 6) | ((m >> 14) & 0x3F);
          u32 base = fineS[F];
          u32 end = base + fineH[F]; if (end > FB_BASE) end = FB_BASE;
          u32 c2 = 0;
          for (u32 j = base; j < end; ++j) c2 += (slots[j] > k) ? 1u : 0u;
          rank = S_top + fineS[F] + c2;
        } else {
          u32 base = FB_BASE + (sufL[cb] - S_cb);
          u32 end = base + histL[cb]; if (end > SLOTN) end = SLOTN;
          u32 c2 = 0;
          for (u32 j = base; j < end; ++j) c2 += (slots[j] > k) ? 1u : 0u;
          rank = sufL[cb] + c2;
        }
        int local = (int)rank - (int)winStart;
        if (local >= 0 && local < rowLimit) perm[local] = ~(u32)k;
      }
    }
    __syncthreads();

    // ---- T6: decode window boxes + areas into LDS (overlays slots/fine) ---
    for (int r = t; r < rowLimit; r += 1024) {
      u32 idx = perm[r];
      float4 bx = decode_box(idx, rb[idx], W, H);
      cboxL[r] = bx;
      careaL[r] = (bx.z - bx.x) * (bx.w - bx.y);
    }
    __syncthreads();

    // ---- T7: greedy NMS, all 16 waves cooperate per 64-candidate block ----
    {
      const int npos = (int)scal[3];
      const int nblk = (rowLimit + 63) >> 6;
      for (int blk = 0; blk < nblk; ++blk) {
        int cnt = (int)scal[2];          // uniform (post-barrier)
        if (cnt >= KEEP_POST) break;
        const int base = blk * 64;
        const int ci = base + lane;
        const bool valid = (ci < rowLimit);
        float4 cur = cboxL[valid ? ci : 0];
        float carea = careaL[valid ? ci : 0];

        // Phase A: kept-list check, kept indices strided across 16 waves
        int dead = 0;
        for (int k = wv; k < cnt; k += 16) {
          float4 kb = kbox[k];
          dead |= (int)iou_sup(kb.x, kb.y, kb.z, kb.w, karea[k],
                               cur.x, cur.y, cur.z, cur.w, carea);
        }
        aw[wv] = __ballot(dead);

        // intra-block 64x64 suppression rows, 4 rows per wave
        #pragma unroll
        for (int q = 0; q < 4; ++q) {
          int j = wv*4 + q;
          int jr = base + j; if (jr >= rowLimit) jr = 0;
          float4 bj = cboxL[jr];
          float ja = careaL[jr];
          bool s = iou_sup(bj.x, bj.y, bj.z, bj.w, ja,
                           cur.x, cur.y, cur.z, cur.w, carea);
          u64 bm = __ballot(s);
          if (lane == 0) mrow[j] = bm;
        }
        __syncthreads();

        // closure: wave 0 bit-sweep (greedy chain)
        if (wv == 0) {
          u64 deadAll = 0;
          #pragma unroll
          for (int k = 0; k < 16; ++k) deadAll |= aw[k];
          int rem = rowLimit - base;
          u64 vm = (rem >= 64) ? ~0ull : ((1ull << rem) - 1ull);
          u64 A = vm & ~deadAll;
          int c2 = cnt;
          while (A && c2 < KEEP_POST) {
            int j = (int)__builtin_ctzll(A);
            A &= A - 1;
            A &= ~mrow[j];               // j's victims (bits > j)
            if (lane == 0) {
              float4 bj = cboxL[base + j];
              kbox[c2] = bj;
              karea[c2] = careaL[base + j];
              ob[c2] = ((int)(winStart + (u32)(base + j)) < npos) ? bj : zero;
            }
            ++c2;
          }
          if (lane == 0) scal[2] = (u32)c2;
        }
        __syncthreads();
      }
    }
    if ((int)scal[2] >= KEEP_POST) break;
  }

  // ---- tail zero-fill (d_out is poisoned before every timed launch) ------
  for (int k2 = (int)scal[2] + t; k2 < KEEP_POST; k2 += 1024) ob[k2] = zero;
}

extern "C" void kernel_launch(void* const* d_in, const int* in_sizes, int n_in,
                              void* d_out, int out_size, void* d_ws, size_t ws_size,
                              hipStream_t stream) {
  const float* preds  = (const float*)d_in[0];
  const float4* regs4 = (const float4*)d_in[1];
  const int* ih       = (const int*)d_in[2];
  const int* iw       = (const int*)d_in[3];
  (void)d_ws; (void)ws_size; (void)in_sizes; (void)n_in; (void)out_size;

  detect_kernel<<<dim3(BS), 1024, 0, stream>>>(
      preds, regs4, ih, iw, (float4*)d_out);
}